// Round 1
// baseline (829.322 us; speedup 1.0000x reference)
//
#include <hip/hip_runtime.h>
#include <math.h>

#define B_ 4
#define T_ 2048
#define DM 256
#define DI 512
#define DS 16
#define DR 16
#define M_ (B_*T_)      // 8192 tokens
#define NCH 32          // scan chunks
#define CLEN (T_/NCH)   // 64 steps per chunk

// ---------------- LayerNorm: one wave per token row ----------------
__device__ __forceinline__ float wave_reduce_sum(float v){
  #pragma unroll
  for(int off=32; off; off>>=1) v += __shfl_xor(v, off, 64);
  return v;
}

__global__ __launch_bounds__(64)
void ln_kernel(const float* __restrict__ x, const float* __restrict__ w,
               const float* __restrict__ b, float* __restrict__ xn){
  int row = blockIdx.x; int lane = threadIdx.x;
  const float4 v = *(const float4*)(x + (size_t)row*DM + lane*4);
  float s  = v.x+v.y+v.z+v.w;
  float sq = v.x*v.x+v.y*v.y+v.z*v.z+v.w*v.w;
  s = wave_reduce_sum(s); sq = wave_reduce_sum(sq);
  float mu  = s*(1.f/DM);
  float var = sq*(1.f/DM) - mu*mu;
  float rs  = rsqrtf(var + 1e-5f);
  const float4 wv = *(const float4*)(w + lane*4);
  const float4 bv = *(const float4*)(b + lane*4);
  float4 o;
  o.x = (v.x-mu)*rs*wv.x + bv.x;
  o.y = (v.y-mu)*rs*wv.y + bv.y;
  o.z = (v.z-mu)*rs*wv.z + bv.z;
  o.w = (v.w-mu)*rs*wv.w + bv.w;
  *(float4*)(xn + (size_t)row*DM + lane*4) = o;
}

// ---------------- fp32 tiled GEMM: C[M,N] = A[M,K] @ W[N,K]^T (+bias)(+resid) ----
#define BM 128
#define BN 64
#define BK 16

__global__ __launch_bounds__(256)
void gemm_nt(const float* __restrict__ A, int lda,
             const float* __restrict__ W, int ldw,
             float* __restrict__ C, int ldc, int K,
             const float* __restrict__ bias,
             const float* __restrict__ resid, int ldr){
  __shared__ float As[BK][BM+4];
  __shared__ float Bs[BK][BN+4];
  const int tid = threadIdx.x;
  const int bm = blockIdx.y * BM;
  const int bn = blockIdx.x * BN;
  const int tx = tid & 15;      // n-subtile
  const int ty = tid >> 4;      // m-subtile
  const int tr = tid >> 2;      // 0..63 load row
  const int tc = (tid & 3)*4;   // k offset

  float acc[8][4] = {};

  for(int k0=0; k0<K; k0+=BK){
    float4 a0 = *(const float4*)(A + (size_t)(bm+tr)*lda    + k0 + tc);
    float4 a1 = *(const float4*)(A + (size_t)(bm+tr+64)*lda + k0 + tc);
    float4 w0 = *(const float4*)(W + (size_t)(bn+tr)*ldw    + k0 + tc);
    __syncthreads();
    As[tc+0][tr] = a0.x; As[tc+1][tr] = a0.y; As[tc+2][tr] = a0.z; As[tc+3][tr] = a0.w;
    As[tc+0][tr+64] = a1.x; As[tc+1][tr+64] = a1.y; As[tc+2][tr+64] = a1.z; As[tc+3][tr+64] = a1.w;
    Bs[tc+0][tr] = w0.x; Bs[tc+1][tr] = w0.y; Bs[tc+2][tr] = w0.z; Bs[tc+3][tr] = w0.w;
    __syncthreads();
    #pragma unroll
    for(int kk=0; kk<BK; ++kk){
      float4 av0 = *(const float4*)&As[kk][ty*8];
      float4 av1 = *(const float4*)&As[kk][ty*8+4];
      float4 bv  = *(const float4*)&Bs[kk][tx*4];
      float am[8] = {av0.x,av0.y,av0.z,av0.w, av1.x,av1.y,av1.z,av1.w};
      float bm4[4] = {bv.x,bv.y,bv.z,bv.w};
      #pragma unroll
      for(int i=0;i<8;++i)
        #pragma unroll
        for(int j=0;j<4;++j)
          acc[i][j] = fmaf(am[i], bm4[j], acc[i][j]);
    }
  }

  const int n0 = bn + tx*4;
  #pragma unroll
  for(int i=0;i<8;++i){
    const int mrow = bm + ty*8 + i;
    float4 val = {acc[i][0],acc[i][1],acc[i][2],acc[i][3]};
    if(bias){
      const float4 bb = *(const float4*)(bias + n0);
      val.x += bb.x; val.y += bb.y; val.z += bb.z; val.w += bb.w;
    }
    if(resid){
      const float4 rr = *(const float4*)(resid + (size_t)mrow*ldr + n0);
      val.x += rr.x; val.y += rr.y; val.z += rr.z; val.w += rr.w;
    }
    *(float4*)(C + (size_t)mrow*ldc + n0) = val;
  }
}

// ---------------- depthwise conv(4) + SiLU (fwd causal / bwd anti-causal) ------
__global__ __launch_bounds__(256)
void conv_silu_kernel(const float* __restrict__ xz,
                      const float* __restrict__ fcw, const float* __restrict__ fcb,
                      const float* __restrict__ bcw, const float* __restrict__ bcb,
                      float* __restrict__ u){
  const int dir = blockIdx.y;
  const int id  = blockIdx.x*256 + threadIdx.x;   // over M_*DI
  const int d   = id & (DI-1);
  const int mt  = id >> 9;
  const int b   = mt >> 11;
  const int t   = mt & (T_-1);
  const float* in = xz + (size_t)dir*M_*1024;
  const float* cw = dir ? bcw : fcw;
  const float* cb = dir ? bcb : fcb;
  float acc = cb[d];
  #pragma unroll
  for(int k=0;k<4;++k){
    const int o = (dir==0) ? (t-3+k) : (t+3-k);
    if(o>=0 && o<T_)
      acc = fmaf(cw[d*4+k], in[((size_t)b*T_+o)*1024 + d], acc);
  }
  const float sg = 1.f/(1.f+__expf(-acc));
  u[(size_t)dir*M_*DI + (size_t)mt*DI + d] = acc*sg;
}

// ---------------- x-proj: per row (dir,m) one wave; out 48 cols ----------------
__global__ __launch_bounds__(256)
void xproj_kernel(const float* __restrict__ u, const float* __restrict__ fxw,
                  const float* __restrict__ bxw, float* __restrict__ xdbl){
  __shared__ float su[4][DI];
  const int tid = threadIdx.x;
  const int wv = tid >> 6, lane = tid & 63;
  const int row = blockIdx.x*4 + wv;
  const int dir = row >> 13, m = row & (M_-1);
  const float* ur = u + (size_t)dir*M_*DI + (size_t)m*DI;
  *(float4*)&su[wv][lane*8]   = *(const float4*)(ur + lane*8);
  *(float4*)&su[wv][lane*8+4] = *(const float4*)(ur + lane*8+4);
  __syncthreads();
  if(lane < 48){
    const float* wr = (dir ? bxw : fxw) + (size_t)lane*DI;
    float acc = 0.f;
    #pragma unroll 4
    for(int k4=0;k4<DI/4;++k4){
      const float4 uu = *(const float4*)&su[wv][k4*4];
      const float4 ww = *(const float4*)(wr + k4*4);
      acc = fmaf(uu.x,ww.x, fmaf(uu.y,ww.y, fmaf(uu.z,ww.z, fmaf(uu.w,ww.w, acc))));
    }
    xdbl[(size_t)dir*M_*48 + (size_t)m*48 + lane] = acc;
  }
}

// ---------------- delta = softplus(dt @ dt_w^T + dt_b) -------------------------
__global__ __launch_bounds__(256)
void delta_kernel(const float* __restrict__ xdbl,
                  const float* __restrict__ fdw, const float* __restrict__ fdb,
                  const float* __restrict__ bdw, const float* __restrict__ bdb,
                  float* __restrict__ delta){
  const size_t id = (size_t)blockIdx.x*256 + threadIdx.x;  // 2*M_*DI
  const int dir = (int)(id >> 22);
  const size_t rem = id & ((1u<<22)-1);
  const int m = (int)(rem >> 9), d = (int)(rem & 511);
  const float* dt = xdbl + (size_t)dir*M_*48 + (size_t)m*48;
  const float* wr = (dir ? bdw : fdw) + d*DR;
  float acc = (dir ? bdb : fdb)[d];
  #pragma unroll
  for(int r=0;r<DR;r+=4){
    const float4 a = *(const float4*)(dt + r);
    const float4 w = *(const float4*)(wr + r);
    acc = fmaf(a.x,w.x, fmaf(a.y,w.y, fmaf(a.z,w.z, fmaf(a.w,w.w, acc))));
  }
  const float sp = fmaxf(acc, 0.f) + log1pf(__expf(-fabsf(acc)));
  delta[(size_t)dir*M_*DI + rem] = sp;
}

// ---------------- scan phase A: per-chunk P=prod(dA), q=tail(h|h0=0) -----------
// lane: c = channel(dir,b,d) [16 lanes/channel], n = state
__global__ __launch_bounds__(256)
void scanA_kernel(const float* __restrict__ delta, const float* __restrict__ u,
                  const float* __restrict__ xdbl,
                  const float* __restrict__ fAlog, const float* __restrict__ bAlog,
                  float* __restrict__ Pb, float* __restrict__ qb){
  const int tid = threadIdx.x;
  const int c = blockIdx.x*16 + (tid>>4);
  const int n = tid & 15;
  const int chunk = blockIdx.y;
  const int dir = c >> 11;
  const int b   = (c >> 9) & 3;
  const int d   = c & 511;
  const float Av = -__expf((dir ? bAlog : fAlog)[d*16+n]);
  const float* dl = delta + (size_t)dir*M_*DI;
  const float* ul = u     + (size_t)dir*M_*DI;
  const float* xd = xdbl  + (size_t)dir*M_*48;
  float h = 0.f, P = 1.f;
  for(int i=0;i<CLEN;++i){
    const int s = chunk*CLEN + i;
    const int t = dir ? (T_-1-s) : s;
    const size_t m = (size_t)b*T_ + t;
    const float dv = dl[m*DI + d];
    const float uv = ul[m*DI + d];
    const float bn = xd[m*48 + 16 + n];
    const float a  = __expf(dv*Av);
    h = fmaf(a, h, dv*bn*uv);
    P *= a;
  }
  const size_t idx = (size_t)chunk*65536 + (size_t)blockIdx.x*256 + tid;
  Pb[idx] = P; qb[idx] = h;
}

// ---------------- scan phase B: sequential chunk combine (tiny) ----------------
__global__ __launch_bounds__(256)
void scanB_kernel(const float* __restrict__ Pb, const float* __restrict__ qb,
                  float* __restrict__ hs){
  const int id = blockIdx.x*256 + threadIdx.x; // 65536 (c,n) pairs
  float h = 0.f;
  for(int ch=0; ch<NCH; ++ch){
    const size_t idx = (size_t)ch*65536 + id;
    hs[idx] = h;
    h = fmaf(Pb[idx], h, qb[idx]);
  }
}

// ---------------- scan phase C: rescan chunk from true h0, emit gated y --------
__global__ __launch_bounds__(256)
void scanC_kernel(const float* __restrict__ delta, const float* __restrict__ u,
                  const float* __restrict__ xdbl, const float* __restrict__ xz,
                  const float* __restrict__ fAlog, const float* __restrict__ bAlog,
                  const float* __restrict__ fD, const float* __restrict__ bD,
                  const float* __restrict__ hs, float* __restrict__ y){
  const int tid = threadIdx.x;
  const int c = blockIdx.x*16 + (tid>>4);
  const int n = tid & 15;
  const int chunk = blockIdx.y;
  const int dir = c >> 11;
  const int b   = (c >> 9) & 3;
  const int d   = c & 511;
  const float Av = -__expf((dir ? bAlog : fAlog)[d*16+n]);
  const float Dd = (dir ? bD : fD)[d];
  const float* dl = delta + (size_t)dir*M_*DI;
  const float* ul = u     + (size_t)dir*M_*DI;
  const float* xd = xdbl  + (size_t)dir*M_*48;
  const float* zl = xz    + (size_t)dir*M_*1024 + 512;
  float h = hs[(size_t)chunk*65536 + (size_t)blockIdx.x*256 + tid];
  for(int i=0;i<CLEN;++i){
    const int s = chunk*CLEN + i;
    const int t = dir ? (T_-1-s) : s;
    const size_t m = (size_t)b*T_ + t;
    const float dv = dl[m*DI + d];
    const float uv = ul[m*DI + d];
    const float bn = xd[m*48 + 16 + n];
    const float cn = xd[m*48 + 32 + n];
    const float a  = __expf(dv*Av);
    h = fmaf(a, h, dv*bn*uv);
    float yp = h*cn;
    yp += __shfl_xor(yp, 1, 64);
    yp += __shfl_xor(yp, 2, 64);
    yp += __shfl_xor(yp, 4, 64);
    yp += __shfl_xor(yp, 8, 64);
    if(n==0){
      const float zv = zl[m*1024 + d];
      const float sg = zv/(1.f+__expf(-zv));
      y[(size_t)dir*M_*DI + m*DI + d] = (yp + uv*Dd)*sg;
    }
  }
}

// -------------------------------------------------------------------------------
extern "C" void kernel_launch(void* const* d_in, const int* in_sizes, int n_in,
                              void* d_out, int out_size, void* d_ws, size_t ws_size,
                              hipStream_t stream) {
  const float* x       = (const float*)d_in[0];
  const float* norm_w  = (const float*)d_in[1];
  const float* norm_b  = (const float*)d_in[2];
  const float* fus_w   = (const float*)d_in[3];
  const float* fus_b   = (const float*)d_in[4];
  const float* f_in_w  = (const float*)d_in[5];
  const float* f_conv_w= (const float*)d_in[6];
  const float* f_conv_b= (const float*)d_in[7];
  const float* f_xproj = (const float*)d_in[8];
  const float* f_dt_w  = (const float*)d_in[9];
  const float* f_dt_b  = (const float*)d_in[10];
  const float* f_A_log = (const float*)d_in[11];
  const float* f_D     = (const float*)d_in[12];
  const float* f_out_w = (const float*)d_in[13];
  const float* b_in_w  = (const float*)d_in[14];
  const float* b_conv_w= (const float*)d_in[15];
  const float* b_conv_b= (const float*)d_in[16];
  const float* b_xproj = (const float*)d_in[17];
  const float* b_dt_w  = (const float*)d_in[18];
  const float* b_dt_b  = (const float*)d_in[19];
  const float* b_A_log = (const float*)d_in[20];
  const float* b_D     = (const float*)d_in[21];
  const float* b_out_w = (const float*)d_in[22];

  float* ws    = (float*)d_ws;
  float* xn    = ws;                                  // M*256
  float* xz    = xn    + (size_t)M_*DM;               // 2*M*1024
  float* u     = xz    + (size_t)2*M_*1024;           // 2*M*512
  float* xdbl  = u     + (size_t)2*M_*DI;             // 2*M*48
  float* delta = xdbl  + (size_t)2*M_*48;             // 2*M*512
  float* yb    = delta + (size_t)2*M_*DI;             // 2*M*512
  float* xcat  = yb    + (size_t)2*M_*DI;             // M*512
  float* Pb    = xcat  + (size_t)M_*DI;               // NCH*65536
  float* qb    = Pb    + (size_t)NCH*65536;           // NCH*65536
  float* hsb   = qb    + (size_t)NCH*65536;           // NCH*65536

  // 1. LayerNorm
  ln_kernel<<<M_, 64, 0, stream>>>(x, norm_w, norm_b, xn);

  // 2. in-proj GEMMs (both directions): xz_dir = xn @ in_w^T  (M x 1024)
  gemm_nt<<<dim3(1024/BN, M_/BM), 256, 0, stream>>>(xn, DM, f_in_w, DM, xz,                 1024, DM, nullptr, nullptr, 0);
  gemm_nt<<<dim3(1024/BN, M_/BM), 256, 0, stream>>>(xn, DM, b_in_w, DM, xz + (size_t)M_*1024,1024, DM, nullptr, nullptr, 0);

  // 3. depthwise conv + SiLU
  conv_silu_kernel<<<dim3(M_*DI/256, 2), 256, 0, stream>>>(xz, f_conv_w, f_conv_b, b_conv_w, b_conv_b, u);

  // 4. x-proj (dt|B|C 48 cols)
  xproj_kernel<<<2*M_/4, 256, 0, stream>>>(u, f_xproj, b_xproj, xdbl);

  // 5. delta = softplus(dt @ dt_w^T + dt_b)
  delta_kernel<<<2*M_*DI/256, 256, 0, stream>>>(xdbl, f_dt_w, f_dt_b, b_dt_w, b_dt_b, delta);

  // 6. chunked scan
  scanA_kernel<<<dim3(256, NCH), 256, 0, stream>>>(delta, u, xdbl, f_A_log, b_A_log, Pb, qb);
  scanB_kernel<<<256, 256, 0, stream>>>(Pb, qb, hsb);
  scanC_kernel<<<dim3(256, NCH), 256, 0, stream>>>(delta, u, xdbl, xz, f_A_log, b_A_log, f_D, b_D, hsb, yb);

  // 7. out-proj GEMMs into concat buffer
  gemm_nt<<<dim3(256/BN, M_/BM), 256, 0, stream>>>(yb,                 DI, f_out_w, DI, xcat,       512, DI, nullptr, nullptr, 0);
  gemm_nt<<<dim3(256/BN, M_/BM), 256, 0, stream>>>(yb + (size_t)M_*DI, DI, b_out_w, DI, xcat + 256, 512, DI, nullptr, nullptr, 0);

  // 8. fusion GEMM + bias + residual -> out
  gemm_nt<<<dim3(256/BN, M_/BM), 256, 0, stream>>>(xcat, DI, fus_w, DI, (float*)d_out, 256, DI, fus_b, x, 256);
}

// Round 2
// 630.130 us; speedup vs baseline: 1.3161x; 1.3161x over previous
//
#include <hip/hip_runtime.h>
#include <math.h>

#define B_ 4
#define T_ 2048
#define DM 256
#define DI 512
#define DS 16
#define DR 16
#define M_ (B_*T_)      // 8192 tokens
#define NCH 32          // scan chunks
#define CLEN (T_/NCH)   // 64 steps per chunk

// ---------------- LayerNorm: one wave per token row ----------------
__device__ __forceinline__ float wave_reduce_sum(float v){
  #pragma unroll
  for(int off=32; off; off>>=1) v += __shfl_xor(v, off, 64);
  return v;
}

__global__ __launch_bounds__(64)
void ln_kernel(const float* __restrict__ x, const float* __restrict__ w,
               const float* __restrict__ b, float* __restrict__ xn){
  int row = blockIdx.x; int lane = threadIdx.x;
  const float4 v = *(const float4*)(x + (size_t)row*DM + lane*4);
  float s  = v.x+v.y+v.z+v.w;
  float sq = v.x*v.x+v.y*v.y+v.z*v.z+v.w*v.w;
  s = wave_reduce_sum(s); sq = wave_reduce_sum(sq);
  float mu  = s*(1.f/DM);
  float var = sq*(1.f/DM) - mu*mu;
  float rs  = rsqrtf(var + 1e-5f);
  const float4 wv = *(const float4*)(w + lane*4);
  const float4 bv = *(const float4*)(b + lane*4);
  float4 o;
  o.x = (v.x-mu)*rs*wv.x + bv.x;
  o.y = (v.y-mu)*rs*wv.y + bv.y;
  o.z = (v.z-mu)*rs*wv.z + bv.z;
  o.w = (v.w-mu)*rs*wv.w + bv.w;
  *(float4*)(xn + (size_t)row*DM + lane*4) = o;
}

// ---------------- fp32 tiled GEMM: C[M,N] = A[M,K] @ W[N,K]^T (+bias)(+resid) ----
#define BM 128
#define BN 64
#define BK 16

__global__ __launch_bounds__(256)
void gemm_nt(const float* __restrict__ A, int lda,
             const float* __restrict__ W, int ldw,
             float* __restrict__ C, int ldc, int K,
             const float* __restrict__ bias,
             const float* __restrict__ resid, int ldr){
  __shared__ float As[BK][BM+4];
  __shared__ float Bs[BK][BN+4];
  const int tid = threadIdx.x;
  const int bm = blockIdx.y * BM;
  const int bn = blockIdx.x * BN;
  const int tx = tid & 15;      // n-subtile
  const int ty = tid >> 4;      // m-subtile
  const int tr = tid >> 2;      // 0..63 load row
  const int tc = (tid & 3)*4;   // k offset

  float acc[8][4] = {};

  for(int k0=0; k0<K; k0+=BK){
    float4 a0 = *(const float4*)(A + (size_t)(bm+tr)*lda    + k0 + tc);
    float4 a1 = *(const float4*)(A + (size_t)(bm+tr+64)*lda + k0 + tc);
    float4 w0 = *(const float4*)(W + (size_t)(bn+tr)*ldw    + k0 + tc);
    __syncthreads();
    As[tc+0][tr] = a0.x; As[tc+1][tr] = a0.y; As[tc+2][tr] = a0.z; As[tc+3][tr] = a0.w;
    As[tc+0][tr+64] = a1.x; As[tc+1][tr+64] = a1.y; As[tc+2][tr+64] = a1.z; As[tc+3][tr+64] = a1.w;
    Bs[tc+0][tr] = w0.x; Bs[tc+1][tr] = w0.y; Bs[tc+2][tr] = w0.z; Bs[tc+3][tr] = w0.w;
    __syncthreads();
    #pragma unroll
    for(int kk=0; kk<BK; ++kk){
      float4 av0 = *(const float4*)&As[kk][ty*8];
      float4 av1 = *(const float4*)&As[kk][ty*8+4];
      float4 bv  = *(const float4*)&Bs[kk][tx*4];
      float am[8] = {av0.x,av0.y,av0.z,av0.w, av1.x,av1.y,av1.z,av1.w};
      float bm4[4] = {bv.x,bv.y,bv.z,bv.w};
      #pragma unroll
      for(int i=0;i<8;++i)
        #pragma unroll
        for(int j=0;j<4;++j)
          acc[i][j] = fmaf(am[i], bm4[j], acc[i][j]);
    }
  }

  const int n0 = bn + tx*4;
  #pragma unroll
  for(int i=0;i<8;++i){
    const int mrow = bm + ty*8 + i;
    float4 val = {acc[i][0],acc[i][1],acc[i][2],acc[i][3]};
    if(bias){
      const float4 bb = *(const float4*)(bias + n0);
      val.x += bb.x; val.y += bb.y; val.z += bb.z; val.w += bb.w;
    }
    if(resid){
      const float4 rr = *(const float4*)(resid + (size_t)mrow*ldr + n0);
      val.x += rr.x; val.y += rr.y; val.z += rr.z; val.w += rr.w;
    }
    *(float4*)(C + (size_t)mrow*ldc + n0) = val;
  }
}

// ---------------- depthwise conv(4) + SiLU (fwd causal / bwd anti-causal) ------
__global__ __launch_bounds__(256)
void conv_silu_kernel(const float* __restrict__ xz,
                      const float* __restrict__ fcw, const float* __restrict__ fcb,
                      const float* __restrict__ bcw, const float* __restrict__ bcb,
                      float* __restrict__ u){
  const int dir = blockIdx.y;
  const int id  = blockIdx.x*256 + threadIdx.x;   // over M_*DI
  const int d   = id & (DI-1);
  const int mt  = id >> 9;
  const int b   = mt >> 11;
  const int t   = mt & (T_-1);
  const float* in = xz + (size_t)dir*M_*1024;
  const float* cw = dir ? bcw : fcw;
  const float* cb = dir ? bcb : fcb;
  float acc = cb[d];
  #pragma unroll
  for(int k=0;k<4;++k){
    const int o = (dir==0) ? (t-3+k) : (t+3-k);
    if(o>=0 && o<T_)
      acc = fmaf(cw[d*4+k], in[((size_t)b*T_+o)*1024 + d], acc);
  }
  const float sg = 1.f/(1.f+__expf(-acc));
  u[(size_t)dir*M_*DI + (size_t)mt*DI + d] = acc*sg;
}

// ---------------- x-proj: per row (dir,m) one wave; out 48 cols ----------------
__global__ __launch_bounds__(256)
void xproj_kernel(const float* __restrict__ u, const float* __restrict__ fxw,
                  const float* __restrict__ bxw, float* __restrict__ xdbl){
  __shared__ float su[4][DI];
  const int tid = threadIdx.x;
  const int wv = tid >> 6, lane = tid & 63;
  const int row = blockIdx.x*4 + wv;
  const int dir = row >> 13, m = row & (M_-1);
  const float* ur = u + (size_t)dir*M_*DI + (size_t)m*DI;
  *(float4*)&su[wv][lane*8]   = *(const float4*)(ur + lane*8);
  *(float4*)&su[wv][lane*8+4] = *(const float4*)(ur + lane*8+4);
  __syncthreads();
  if(lane < 48){
    const float* wr = (dir ? bxw : fxw) + (size_t)lane*DI;
    float acc = 0.f;
    #pragma unroll 4
    for(int k4=0;k4<DI/4;++k4){
      const float4 uu = *(const float4*)&su[wv][k4*4];
      const float4 ww = *(const float4*)(wr + k4*4);
      acc = fmaf(uu.x,ww.x, fmaf(uu.y,ww.y, fmaf(uu.z,ww.z, fmaf(uu.w,ww.w, acc))));
    }
    xdbl[(size_t)dir*M_*48 + (size_t)m*48 + lane] = acc;
  }
}

// ---------------- delta = softplus(dt @ dt_w^T + dt_b) -------------------------
__global__ __launch_bounds__(256)
void delta_kernel(const float* __restrict__ xdbl,
                  const float* __restrict__ fdw, const float* __restrict__ fdb,
                  const float* __restrict__ bdw, const float* __restrict__ bdb,
                  float* __restrict__ delta){
  const size_t id = (size_t)blockIdx.x*256 + threadIdx.x;  // 2*M_*DI
  const int dir = (int)(id >> 22);
  const size_t rem = id & ((1u<<22)-1);
  const int m = (int)(rem >> 9), d = (int)(rem & 511);
  const float* dt = xdbl + (size_t)dir*M_*48 + (size_t)m*48;
  const float* wr = (dir ? bdw : fdw) + d*DR;
  float acc = (dir ? bdb : fdb)[d];
  #pragma unroll
  for(int r=0;r<DR;r+=4){
    const float4 a = *(const float4*)(dt + r);
    const float4 w = *(const float4*)(wr + r);
    acc = fmaf(a.x,w.x, fmaf(a.y,w.y, fmaf(a.z,w.z, fmaf(a.w,w.w, acc))));
  }
  const float sp = fmaxf(acc, 0.f) + log1pf(__expf(-fabsf(acc)));
  delta[(size_t)dir*M_*DI + rem] = sp;
}

// ======== scan v2: one thread per channel, 16 states in registers ========
// block: 256 threads = 256 channels (half of DI); grid.x = dir*8 + b*2 + half,
// grid.y = chunk. B/C rows for the chunk staged in LDS, broadcast-read.

__global__ __launch_bounds__(256)
void scanA_kernel(const float* __restrict__ delta, const float* __restrict__ u,
                  const float* __restrict__ xdbl,
                  const float* __restrict__ fAlog, const float* __restrict__ bAlog,
                  float* __restrict__ Pb, float* __restrict__ qb){
  __shared__ float sB[CLEN][16];
  const int tid  = threadIdx.x;
  const int bx   = blockIdx.x;
  const int dir  = bx >> 3;
  const int b    = (bx >> 1) & 3;
  const int half = bx & 1;
  const int chunk= blockIdx.y;
  const int d    = half*256 + tid;
  const int i0   = chunk*CLEN;

  // stage B rows: CLEN x 16 floats = 256 float4s, one per thread
  {
    const int r = tid >> 2, c4 = (tid & 3) * 4;
    const int t = dir ? (T_-1-(i0+r)) : (i0+r);
    const float4 v = *(const float4*)(xdbl + (size_t)dir*M_*48 + ((size_t)b*T_+t)*48 + 16 + c4);
    *(float4*)&sB[r][c4] = v;
  }

  float Av[16];
  {
    const float* al = (dir ? bAlog : fAlog) + d*16;
    #pragma unroll
    for(int g=0; g<4; ++g){
      float4 v = *(const float4*)(al + g*4);
      Av[g*4+0] = -__expf(v.x); Av[g*4+1] = -__expf(v.y);
      Av[g*4+2] = -__expf(v.z); Av[g*4+3] = -__expf(v.w);
    }
  }
  __syncthreads();

  const int t0 = dir ? (T_-1-i0) : i0;
  const ptrdiff_t sst = dir ? -DI : DI;
  const float* dp = delta + (size_t)dir*M_*DI + ((size_t)b*T_+t0)*DI + d;
  const float* up = u     + (size_t)dir*M_*DI + ((size_t)b*T_+t0)*DI + d;

  float h[16]; float P[16];
  #pragma unroll
  for(int n=0;n<16;++n){ h[n]=0.f; P[n]=1.f; }

  float dv = *dp, uv = *up;
  for(int i=0; i<CLEN; ++i){
    dp += sst; up += sst;
    const float dvn = *dp, uvn = *up;      // prefetch (one-past-end stays in ws)
    const float du = dv*uv;
    float4 bn0 = *(const float4*)&sB[i][0];
    float4 bn1 = *(const float4*)&sB[i][4];
    float4 bn2 = *(const float4*)&sB[i][8];
    float4 bn3 = *(const float4*)&sB[i][12];
    const float bl[16] = {bn0.x,bn0.y,bn0.z,bn0.w, bn1.x,bn1.y,bn1.z,bn1.w,
                          bn2.x,bn2.y,bn2.z,bn2.w, bn3.x,bn3.y,bn3.z,bn3.w};
    #pragma unroll
    for(int n=0;n<16;++n){
      const float a = __expf(dv*Av[n]);
      h[n] = fmaf(a, h[n], du*bl[n]);
      P[n] *= a;
    }
    dv = dvn; uv = uvn;
  }

  float* Pp = Pb + (size_t)chunk*65536 + (((size_t)(dir*4+b)*512 + d)<<4);
  float* qp = qb + (size_t)chunk*65536 + (((size_t)(dir*4+b)*512 + d)<<4);
  #pragma unroll
  for(int g=0; g<4; ++g){
    *(float4*)(Pp + g*4) = make_float4(P[g*4],P[g*4+1],P[g*4+2],P[g*4+3]);
    *(float4*)(qp + g*4) = make_float4(h[g*4],h[g*4+1],h[g*4+2],h[g*4+3]);
  }
}

__global__ __launch_bounds__(256)
void scanB_kernel(const float* __restrict__ Pb, const float* __restrict__ qb,
                  float* __restrict__ hs){
  const int id = blockIdx.x*256 + threadIdx.x; // 65536 (c,n) pairs
  float h = 0.f;
  for(int ch=0; ch<NCH; ++ch){
    const size_t idx = (size_t)ch*65536 + id;
    hs[idx] = h;
    h = fmaf(Pb[idx], h, qb[idx]);
  }
}

__global__ __launch_bounds__(256)
void scanC_kernel(const float* __restrict__ delta, const float* __restrict__ u,
                  const float* __restrict__ xdbl, const float* __restrict__ xz,
                  const float* __restrict__ fAlog, const float* __restrict__ bAlog,
                  const float* __restrict__ fD, const float* __restrict__ bD,
                  const float* __restrict__ hs, float* __restrict__ y){
  __shared__ float sBC[CLEN][32];
  const int tid  = threadIdx.x;
  const int bx   = blockIdx.x;
  const int dir  = bx >> 3;
  const int b    = (bx >> 1) & 3;
  const int half = bx & 1;
  const int chunk= blockIdx.y;
  const int d    = half*256 + tid;
  const int i0   = chunk*CLEN;

  // stage B|C rows: CLEN x 32 floats = 512 float4s, two per thread
  {
    #pragma unroll
    for(int rep=0; rep<2; ++rep){
      const int j = tid + rep*256;
      const int r = j >> 3, c4 = (j & 7) * 4;
      const int t = dir ? (T_-1-(i0+r)) : (i0+r);
      const float4 v = *(const float4*)(xdbl + (size_t)dir*M_*48 + ((size_t)b*T_+t)*48 + 16 + c4);
      *(float4*)&sBC[r][c4] = v;
    }
  }

  float Av[16];
  {
    const float* al = (dir ? bAlog : fAlog) + d*16;
    #pragma unroll
    for(int g=0; g<4; ++g){
      float4 v = *(const float4*)(al + g*4);
      Av[g*4+0] = -__expf(v.x); Av[g*4+1] = -__expf(v.y);
      Av[g*4+2] = -__expf(v.z); Av[g*4+3] = -__expf(v.w);
    }
  }
  const float Dd = (dir ? bD : fD)[d];

  float h[16];
  {
    const float* hp = hs + (size_t)chunk*65536 + (((size_t)(dir*4+b)*512 + d)<<4);
    #pragma unroll
    for(int g=0; g<4; ++g){
      float4 v = *(const float4*)(hp + g*4);
      h[g*4]=v.x; h[g*4+1]=v.y; h[g*4+2]=v.z; h[g*4+3]=v.w;
    }
  }
  __syncthreads();

  const int t0 = dir ? (T_-1-i0) : i0;
  const ptrdiff_t sst = dir ? -DI : DI;
  const ptrdiff_t zst = dir ? -1024 : 1024;
  const float* dp = delta + (size_t)dir*M_*DI + ((size_t)b*T_+t0)*DI + d;
  const float* up = u     + (size_t)dir*M_*DI + ((size_t)b*T_+t0)*DI + d;
  const float* zp = xz    + (size_t)dir*M_*1024 + ((size_t)b*T_+t0)*1024 + 512 + d;
  float*       yp = y     + (size_t)dir*M_*DI + ((size_t)b*T_+t0)*DI + d;

  float dv = *dp, uv = *up, zv = *zp;
  for(int i=0; i<CLEN; ++i){
    dp += sst; up += sst; zp += zst;
    const float dvn = *dp, uvn = *up, zvn = *zp;  // prefetch
    const float du = dv*uv;
    float4 b0 = *(const float4*)&sBC[i][0];
    float4 b1 = *(const float4*)&sBC[i][4];
    float4 b2 = *(const float4*)&sBC[i][8];
    float4 b3 = *(const float4*)&sBC[i][12];
    float4 c0 = *(const float4*)&sBC[i][16];
    float4 c1 = *(const float4*)&sBC[i][20];
    float4 c2 = *(const float4*)&sBC[i][24];
    float4 c3 = *(const float4*)&sBC[i][28];
    const float bl[16] = {b0.x,b0.y,b0.z,b0.w, b1.x,b1.y,b1.z,b1.w,
                          b2.x,b2.y,b2.z,b2.w, b3.x,b3.y,b3.z,b3.w};
    const float cl[16] = {c0.x,c0.y,c0.z,c0.w, c1.x,c1.y,c1.z,c1.w,
                          c2.x,c2.y,c2.z,c2.w, c3.x,c3.y,c3.z,c3.w};
    float y0=0.f, y1=0.f, y2=0.f, y3=0.f;
    #pragma unroll
    for(int n=0;n<16;n+=4){
      float a0 = __expf(dv*Av[n+0]);
      float a1 = __expf(dv*Av[n+1]);
      float a2 = __expf(dv*Av[n+2]);
      float a3 = __expf(dv*Av[n+3]);
      h[n+0] = fmaf(a0, h[n+0], du*bl[n+0]);
      h[n+1] = fmaf(a1, h[n+1], du*bl[n+1]);
      h[n+2] = fmaf(a2, h[n+2], du*bl[n+2]);
      h[n+3] = fmaf(a3, h[n+3], du*bl[n+3]);
      y0 = fmaf(h[n+0], cl[n+0], y0);
      y1 = fmaf(h[n+1], cl[n+1], y1);
      y2 = fmaf(h[n+2], cl[n+2], y2);
      y3 = fmaf(h[n+3], cl[n+3], y3);
    }
    const float sg = __fdividef(zv, 1.f + __expf(-zv));
    *yp = (((y0+y1)+(y2+y3)) + uv*Dd) * sg;
    yp += sst;
    dv = dvn; uv = uvn; zv = zvn;
  }
}

// -------------------------------------------------------------------------------
extern "C" void kernel_launch(void* const* d_in, const int* in_sizes, int n_in,
                              void* d_out, int out_size, void* d_ws, size_t ws_size,
                              hipStream_t stream) {
  const float* x       = (const float*)d_in[0];
  const float* norm_w  = (const float*)d_in[1];
  const float* norm_b  = (const float*)d_in[2];
  const float* fus_w   = (const float*)d_in[3];
  const float* fus_b   = (const float*)d_in[4];
  const float* f_in_w  = (const float*)d_in[5];
  const float* f_conv_w= (const float*)d_in[6];
  const float* f_conv_b= (const float*)d_in[7];
  const float* f_xproj = (const float*)d_in[8];
  const float* f_dt_w  = (const float*)d_in[9];
  const float* f_dt_b  = (const float*)d_in[10];
  const float* f_A_log = (const float*)d_in[11];
  const float* f_D     = (const float*)d_in[12];
  const float* f_out_w = (const float*)d_in[13];
  const float* b_in_w  = (const float*)d_in[14];
  const float* b_conv_w= (const float*)d_in[15];
  const float* b_conv_b= (const float*)d_in[16];
  const float* b_xproj = (const float*)d_in[17];
  const float* b_dt_w  = (const float*)d_in[18];
  const float* b_dt_b  = (const float*)d_in[19];
  const float* b_A_log = (const float*)d_in[20];
  const float* b_D     = (const float*)d_in[21];
  const float* b_out_w = (const float*)d_in[22];

  float* ws    = (float*)d_ws;
  float* xn    = ws;                                  // M*256
  float* xz    = xn    + (size_t)M_*DM;               // 2*M*1024
  float* u     = xz    + (size_t)2*M_*1024;           // 2*M*512
  float* xdbl  = u     + (size_t)2*M_*DI;             // 2*M*48
  float* delta = xdbl  + (size_t)2*M_*48;             // 2*M*512
  float* yb    = delta + (size_t)2*M_*DI;             // 2*M*512
  float* xcat  = yb    + (size_t)2*M_*DI;             // M*512
  float* Pb    = xcat  + (size_t)M_*DI;               // NCH*65536
  float* qb    = Pb    + (size_t)NCH*65536;           // NCH*65536
  float* hsb   = qb    + (size_t)NCH*65536;           // NCH*65536

  // 1. LayerNorm
  ln_kernel<<<M_, 64, 0, stream>>>(x, norm_w, norm_b, xn);

  // 2. in-proj GEMMs (both directions): xz_dir = xn @ in_w^T  (M x 1024)
  gemm_nt<<<dim3(1024/BN, M_/BM), 256, 0, stream>>>(xn, DM, f_in_w, DM, xz,                 1024, DM, nullptr, nullptr, 0);
  gemm_nt<<<dim3(1024/BN, M_/BM), 256, 0, stream>>>(xn, DM, b_in_w, DM, xz + (size_t)M_*1024,1024, DM, nullptr, nullptr, 0);

  // 3. depthwise conv + SiLU
  conv_silu_kernel<<<dim3(M_*DI/256, 2), 256, 0, stream>>>(xz, f_conv_w, f_conv_b, b_conv_w, b_conv_b, u);

  // 4. x-proj (dt|B|C 48 cols)
  xproj_kernel<<<2*M_/4, 256, 0, stream>>>(u, f_xproj, b_xproj, xdbl);

  // 5. delta = softplus(dt @ dt_w^T + dt_b)
  delta_kernel<<<2*M_*DI/256, 256, 0, stream>>>(xdbl, f_dt_w, f_dt_b, b_dt_w, b_dt_b, delta);

  // 6. chunked scan (v2: states-in-registers)
  scanA_kernel<<<dim3(16, NCH), 256, 0, stream>>>(delta, u, xdbl, f_A_log, b_A_log, Pb, qb);
  scanB_kernel<<<256, 256, 0, stream>>>(Pb, qb, hsb);
  scanC_kernel<<<dim3(16, NCH), 256, 0, stream>>>(delta, u, xdbl, xz, f_A_log, b_A_log, f_D, b_D, hsb, yb);

  // 7. out-proj GEMMs into concat buffer
  gemm_nt<<<dim3(256/BN, M_/BM), 256, 0, stream>>>(yb,                 DI, f_out_w, DI, xcat,       512, DI, nullptr, nullptr, 0);
  gemm_nt<<<dim3(256/BN, M_/BM), 256, 0, stream>>>(yb + (size_t)M_*DI, DI, b_out_w, DI, xcat + 256, 512, DI, nullptr, nullptr, 0);

  // 8. fusion GEMM + bias + residual -> out
  gemm_nt<<<dim3(256/BN, M_/BM), 256, 0, stream>>>(xcat, DI, fus_w, DI, (float*)d_out, 256, DI, fus_b, x, 256);
}

// Round 3
// 300.898 us; speedup vs baseline: 2.7562x; 2.0942x over previous
//
#include <hip/hip_runtime.h>
#include <math.h>

#define B_ 4
#define T_ 2048
#define DM 256
#define DI 512
#define DS 16
#define DR 16
#define M_ (B_*T_)      // 8192 tokens
#define NCH 32          // scan chunks
#define CLEN (T_/NCH)   // 64 steps per chunk
#define XDS 64          // xdbl row stride (padded from 48)

typedef __attribute__((ext_vector_type(8))) short short8;
typedef __attribute__((ext_vector_type(4))) float f32x4;

__device__ __forceinline__ unsigned short f2bf(float f){
  unsigned u = __builtin_bit_cast(unsigned, f);
  u += 0x7fff + ((u >> 16) & 1);          // RNE
  return (unsigned short)(u >> 16);
}

// ---------------- LayerNorm: one wave per token row -> bf16 out ----------------
__device__ __forceinline__ float wave_reduce_sum(float v){
  #pragma unroll
  for(int off=32; off; off>>=1) v += __shfl_xor(v, off, 64);
  return v;
}

__global__ __launch_bounds__(64)
void ln_kernel(const float* __restrict__ x, const float* __restrict__ w,
               const float* __restrict__ b, unsigned short* __restrict__ xnb){
  int row = blockIdx.x; int lane = threadIdx.x;
  const float4 v = *(const float4*)(x + (size_t)row*DM + lane*4);
  float s  = v.x+v.y+v.z+v.w;
  float sq = v.x*v.x+v.y*v.y+v.z*v.z+v.w*v.w;
  s = wave_reduce_sum(s); sq = wave_reduce_sum(sq);
  float mu  = s*(1.f/DM);
  float var = sq*(1.f/DM) - mu*mu;
  float rs  = rsqrtf(var + 1e-5f);
  const float4 wv = *(const float4*)(w + lane*4);
  const float4 bv = *(const float4*)(b + lane*4);
  ushort4 o;
  o.x = f2bf((v.x-mu)*rs*wv.x + bv.x);
  o.y = f2bf((v.y-mu)*rs*wv.y + bv.y);
  o.z = f2bf((v.z-mu)*rs*wv.z + bv.z);
  o.w = f2bf((v.w-mu)*rs*wv.w + bv.w);
  *(ushort4*)(xnb + (size_t)row*DM + lane*4) = o;
}

// ---------------- weight fp32 -> bf16 conversion (incl. padded xproj) ----------
__global__ __launch_bounds__(256)
void wconv_kernel(const float* __restrict__ f_in_w, const float* __restrict__ b_in_w,
                  const float* __restrict__ f_out_w, const float* __restrict__ b_out_w,
                  const float* __restrict__ fus_w,
                  const float* __restrict__ f_xp, const float* __restrict__ b_xp,
                  unsigned short* __restrict__ dst){
  const int idx = blockIdx.x*256 + threadIdx.x;   // 983040 total
  float v;
  if      (idx < 262144) v = f_in_w[idx];
  else if (idx < 524288) v = b_in_w[idx-262144];
  else if (idx < 655360) v = f_out_w[idx-524288];
  else if (idx < 786432) v = b_out_w[idx-655360];
  else if (idx < 917504) v = fus_w[idx-786432];
  else if (idx < 950272){ int j = idx-917504; v = (j < 48*512) ? f_xp[j] : 0.f; }
  else                  { int j = idx-950272; v = (j < 48*512) ? b_xp[j] : 0.f; }
  dst[idx] = f2bf(v);
}

// ---------------- bf16 MFMA GEMM: C[M,N] = A[M,K] @ W[N,K]^T (+bias)(+resid) ---
// 128x64 tile, BK=32, 256 threads = 4 waves; wave w -> rows [w*32, w*32+32).
#define GBM 128
#define GBN 64
#define GBK 32

__device__ __forceinline__ void store_out(float* p, float v){ *p = v; }
__device__ __forceinline__ void store_out(unsigned short* p, float v){ *p = f2bf(v); }

template<typename OutT>
__global__ __launch_bounds__(256)
void gemm_mfma(const unsigned short* __restrict__ A, int lda,
               const unsigned short* __restrict__ W, int ldw,
               OutT* __restrict__ C, int ldc, int K,
               const float* __restrict__ bias,
               const float* __restrict__ resid, int ldr){
  __shared__ unsigned short As[GBM*40];   // row stride 40 bf16 (80B): 2-way conflicts only
  __shared__ unsigned short Ws[GBN*40];
  const int tid = threadIdx.x;
  const int bm = blockIdx.y * GBM;
  const int bn = blockIdx.x * GBN;

  const int srow = tid >> 2;
  const int scol = (tid & 3) * 8;
  const unsigned short* Ag = A + (size_t)(bm + srow)*lda + scol;
  const unsigned short* Wg = W + (size_t)(bn + srow)*ldw + scol;

  const int wid = tid >> 6;
  const int lr  = tid & 15;
  const int lk  = ((tid >> 4) & 3) * 8;

  f32x4 acc[2][4];
  #pragma unroll
  for(int i=0;i<2;++i)
    #pragma unroll
    for(int j=0;j<4;++j) acc[i][j] = (f32x4){0.f,0.f,0.f,0.f};

  for(int k0=0; k0<K; k0+=GBK){
    const uint4 a0 = *(const uint4*)(Ag + k0);
    const uint4 a1 = *(const uint4*)(Ag + (size_t)64*lda + k0);
    const uint4 w0 = *(const uint4*)(Wg + k0);
    __syncthreads();
    *(uint4*)&As[srow*40 + scol]      = a0;
    *(uint4*)&As[(srow+64)*40 + scol] = a1;
    *(uint4*)&Ws[srow*40 + scol]      = w0;
    __syncthreads();

    const short8 af0 = *(const short8*)&As[(wid*32 + lr)*40 + lk];
    const short8 af1 = *(const short8*)&As[(wid*32 + 16 + lr)*40 + lk];
    #pragma unroll
    for(int nt=0; nt<4; ++nt){
      const short8 bfr = *(const short8*)&Ws[(nt*16 + lr)*40 + lk];
      acc[0][nt] = __builtin_amdgcn_mfma_f32_16x16x32_bf16(af0, bfr, acc[0][nt], 0, 0, 0);
      acc[1][nt] = __builtin_amdgcn_mfma_f32_16x16x32_bf16(af1, bfr, acc[1][nt], 0, 0, 0);
    }
  }

  // C/D layout: col = lane&15, row = (lane>>4)*4 + reg  [m89 verified]
  const int rg = (tid >> 4) & 3;
  #pragma unroll
  for(int mt=0; mt<2; ++mt){
    const int r0 = bm + wid*32 + mt*16 + rg*4;
    #pragma unroll
    for(int nt=0; nt<4; ++nt){
      const int c = bn + nt*16 + lr;
      #pragma unroll
      for(int r=0; r<4; ++r){
        float v = acc[mt][nt][r];
        if(bias)  v += bias[c];
        if(resid) v += resid[(size_t)(r0+r)*ldr + c];
        store_out(&C[(size_t)(r0+r)*ldc + c], v);
      }
    }
  }
}

// ---------------- depthwise conv(4) + SiLU -> fp32 u + bf16 u ------------------
__global__ __launch_bounds__(256)
void conv_silu_kernel(const float* __restrict__ xz,
                      const float* __restrict__ fcw, const float* __restrict__ fcb,
                      const float* __restrict__ bcw, const float* __restrict__ bcb,
                      float* __restrict__ u, unsigned short* __restrict__ ub){
  const int dir = blockIdx.y;
  const int id  = blockIdx.x*256 + threadIdx.x;   // over M_*DI
  const int d   = id & (DI-1);
  const int mt  = id >> 9;
  const int b   = mt >> 11;
  const int t   = mt & (T_-1);
  const float* in = xz + (size_t)dir*M_*1024;
  const float* cw = dir ? bcw : fcw;
  const float* cb = dir ? bcb : fcb;
  float acc = cb[d];
  #pragma unroll
  for(int k=0;k<4;++k){
    const int o = (dir==0) ? (t-3+k) : (t+3-k);
    if(o>=0 && o<T_)
      acc = fmaf(cw[d*4+k], in[((size_t)b*T_+o)*1024 + d], acc);
  }
  const float sg = 1.f/(1.f+__expf(-acc));
  const float val = acc*sg;
  const size_t oi = (size_t)dir*M_*DI + (size_t)mt*DI + d;
  u[oi] = val;
  ub[oi] = f2bf(val);
}

// ---------------- delta = softplus(dt @ dt_w^T + dt_b) (xdbl stride 64) --------
__global__ __launch_bounds__(256)
void delta_kernel(const float* __restrict__ xdbl,
                  const float* __restrict__ fdw, const float* __restrict__ fdb,
                  const float* __restrict__ bdw, const float* __restrict__ bdb,
                  float* __restrict__ delta){
  const size_t id = (size_t)blockIdx.x*256 + threadIdx.x;  // 2*M_*DI
  const int dir = (int)(id >> 22);
  const size_t rem = id & ((1u<<22)-1);
  const int m = (int)(rem >> 9), d = (int)(rem & 511);
  const float* dt = xdbl + (size_t)dir*M_*XDS + (size_t)m*XDS;
  const float* wr = (dir ? bdw : fdw) + d*DR;
  float acc = (dir ? bdb : fdb)[d];
  #pragma unroll
  for(int r=0;r<DR;r+=4){
    const float4 a = *(const float4*)(dt + r);
    const float4 w = *(const float4*)(wr + r);
    acc = fmaf(a.x,w.x, fmaf(a.y,w.y, fmaf(a.z,w.z, fmaf(a.w,w.w, acc))));
  }
  const float sp = fmaxf(acc, 0.f) + log1pf(__expf(-fabsf(acc)));
  delta[(size_t)dir*M_*DI + rem] = sp;
}

// ======== scan: one thread per channel, 16 states in registers ========
__global__ __launch_bounds__(256)
void scanA_kernel(const float* __restrict__ delta, const float* __restrict__ u,
                  const float* __restrict__ xdbl,
                  const float* __restrict__ fAlog, const float* __restrict__ bAlog,
                  float* __restrict__ Pb, float* __restrict__ qb){
  __shared__ float sB[CLEN][16];
  const int tid  = threadIdx.x;
  const int bx   = blockIdx.x;
  const int dir  = bx >> 3;
  const int b    = (bx >> 1) & 3;
  const int half = bx & 1;
  const int chunk= blockIdx.y;
  const int d    = half*256 + tid;
  const int i0   = chunk*CLEN;

  {
    const int r = tid >> 2, c4 = (tid & 3) * 4;
    const int t = dir ? (T_-1-(i0+r)) : (i0+r);
    const float4 v = *(const float4*)(xdbl + (size_t)dir*M_*XDS + ((size_t)b*T_+t)*XDS + 16 + c4);
    *(float4*)&sB[r][c4] = v;
  }

  float Av[16];
  {
    const float* al = (dir ? bAlog : fAlog) + d*16;
    #pragma unroll
    for(int g=0; g<4; ++g){
      float4 v = *(const float4*)(al + g*4);
      Av[g*4+0] = -__expf(v.x); Av[g*4+1] = -__expf(v.y);
      Av[g*4+2] = -__expf(v.z); Av[g*4+3] = -__expf(v.w);
    }
  }
  __syncthreads();

  const int t0 = dir ? (T_-1-i0) : i0;
  const ptrdiff_t sst = dir ? -DI : DI;
  const float* dp = delta + (size_t)dir*M_*DI + ((size_t)b*T_+t0)*DI + d;
  const float* up = u     + (size_t)dir*M_*DI + ((size_t)b*T_+t0)*DI + d;

  float h[16]; float P[16];
  #pragma unroll
  for(int n=0;n<16;++n){ h[n]=0.f; P[n]=1.f; }

  float dv = *dp, uv = *up;
  for(int i=0; i<CLEN; ++i){
    dp += sst; up += sst;
    const float dvn = *dp, uvn = *up;      // prefetch (one-past-end stays in ws)
    const float du = dv*uv;
    float4 bn0 = *(const float4*)&sB[i][0];
    float4 bn1 = *(const float4*)&sB[i][4];
    float4 bn2 = *(const float4*)&sB[i][8];
    float4 bn3 = *(const float4*)&sB[i][12];
    const float bl[16] = {bn0.x,bn0.y,bn0.z,bn0.w, bn1.x,bn1.y,bn1.z,bn1.w,
                          bn2.x,bn2.y,bn2.z,bn2.w, bn3.x,bn3.y,bn3.z,bn3.w};
    #pragma unroll
    for(int n=0;n<16;++n){
      const float a = __expf(dv*Av[n]);
      h[n] = fmaf(a, h[n], du*bl[n]);
      P[n] *= a;
    }
    dv = dvn; uv = uvn;
  }

  float* Pp = Pb + (size_t)chunk*65536 + (((size_t)(dir*4+b)*512 + d)<<4);
  float* qp = qb + (size_t)chunk*65536 + (((size_t)(dir*4+b)*512 + d)<<4);
  #pragma unroll
  for(int g=0; g<4; ++g){
    *(float4*)(Pp + g*4) = make_float4(P[g*4],P[g*4+1],P[g*4+2],P[g*4+3]);
    *(float4*)(qp + g*4) = make_float4(h[g*4],h[g*4+1],h[g*4+2],h[g*4+3]);
  }
}

__global__ __launch_bounds__(256)
void scanB_kernel(const float* __restrict__ Pb, const float* __restrict__ qb,
                  float* __restrict__ hs){
  const int id = blockIdx.x*256 + threadIdx.x; // 65536 (c,n) pairs
  float h = 0.f;
  for(int ch=0; ch<NCH; ++ch){
    const size_t idx = (size_t)ch*65536 + id;
    hs[idx] = h;
    h = fmaf(Pb[idx], h, qb[idx]);
  }
}

__global__ __launch_bounds__(256)
void scanC_kernel(const float* __restrict__ delta, const float* __restrict__ u,
                  const float* __restrict__ xdbl, const float* __restrict__ xz,
                  const float* __restrict__ fAlog, const float* __restrict__ bAlog,
                  const float* __restrict__ fD, const float* __restrict__ bD,
                  const float* __restrict__ hs, unsigned short* __restrict__ yb){
  __shared__ float sBC[CLEN][32];
  const int tid  = threadIdx.x;
  const int bx   = blockIdx.x;
  const int dir  = bx >> 3;
  const int b    = (bx >> 1) & 3;
  const int half = bx & 1;
  const int chunk= blockIdx.y;
  const int d    = half*256 + tid;
  const int i0   = chunk*CLEN;

  {
    #pragma unroll
    for(int rep=0; rep<2; ++rep){
      const int j = tid + rep*256;
      const int r = j >> 3, c4 = (j & 7) * 4;
      const int t = dir ? (T_-1-(i0+r)) : (i0+r);
      const float4 v = *(const float4*)(xdbl + (size_t)dir*M_*XDS + ((size_t)b*T_+t)*XDS + 16 + c4);
      *(float4*)&sBC[r][c4] = v;
    }
  }

  float Av[16];
  {
    const float* al = (dir ? bAlog : fAlog) + d*16;
    #pragma unroll
    for(int g=0; g<4; ++g){
      float4 v = *(const float4*)(al + g*4);
      Av[g*4+0] = -__expf(v.x); Av[g*4+1] = -__expf(v.y);
      Av[g*4+2] = -__expf(v.z); Av[g*4+3] = -__expf(v.w);
    }
  }
  const float Dd = (dir ? bD : fD)[d];

  float h[16];
  {
    const float* hp = hs + (size_t)chunk*65536 + (((size_t)(dir*4+b)*512 + d)<<4);
    #pragma unroll
    for(int g=0; g<4; ++g){
      float4 v = *(const float4*)(hp + g*4);
      h[g*4]=v.x; h[g*4+1]=v.y; h[g*4+2]=v.z; h[g*4+3]=v.w;
    }
  }
  __syncthreads();

  const int t0 = dir ? (T_-1-i0) : i0;
  const ptrdiff_t sst = dir ? -DI : DI;
  const ptrdiff_t zst = dir ? -1024 : 1024;
  const float* dp = delta + (size_t)dir*M_*DI + ((size_t)b*T_+t0)*DI + d;
  const float* up = u     + (size_t)dir*M_*DI + ((size_t)b*T_+t0)*DI + d;
  const float* zp = xz    + (size_t)dir*M_*1024 + ((size_t)b*T_+t0)*1024 + 512 + d;
  unsigned short* yp = yb + (size_t)dir*M_*DI + ((size_t)b*T_+t0)*DI + d;

  float dv = *dp, uv = *up, zv = *zp;
  for(int i=0; i<CLEN; ++i){
    dp += sst; up += sst; zp += zst;
    const float dvn = *dp, uvn = *up, zvn = *zp;  // prefetch
    const float du = dv*uv;
    float4 b0 = *(const float4*)&sBC[i][0];
    float4 b1 = *(const float4*)&sBC[i][4];
    float4 b2 = *(const float4*)&sBC[i][8];
    float4 b3 = *(const float4*)&sBC[i][12];
    float4 c0 = *(const float4*)&sBC[i][16];
    float4 c1 = *(const float4*)&sBC[i][20];
    float4 c2 = *(const float4*)&sBC[i][24];
    float4 c3 = *(const float4*)&sBC[i][28];
    const float bl[16] = {b0.x,b0.y,b0.z,b0.w, b1.x,b1.y,b1.z,b1.w,
                          b2.x,b2.y,b2.z,b2.w, b3.x,b3.y,b3.z,b3.w};
    const float cl[16] = {c0.x,c0.y,c0.z,c0.w, c1.x,c1.y,c1.z,c1.w,
                          c2.x,c2.y,c2.z,c2.w, c3.x,c3.y,c3.z,c3.w};
    float y0=0.f, y1=0.f, y2=0.f, y3=0.f;
    #pragma unroll
    for(int n=0;n<16;n+=4){
      float a0 = __expf(dv*Av[n+0]);
      float a1 = __expf(dv*Av[n+1]);
      float a2 = __expf(dv*Av[n+2]);
      float a3 = __expf(dv*Av[n+3]);
      h[n+0] = fmaf(a0, h[n+0], du*bl[n+0]);
      h[n+1] = fmaf(a1, h[n+1], du*bl[n+1]);
      h[n+2] = fmaf(a2, h[n+2], du*bl[n+2]);
      h[n+3] = fmaf(a3, h[n+3], du*bl[n+3]);
      y0 = fmaf(h[n+0], cl[n+0], y0);
      y1 = fmaf(h[n+1], cl[n+1], y1);
      y2 = fmaf(h[n+2], cl[n+2], y2);
      y3 = fmaf(h[n+3], cl[n+3], y3);
    }
    const float sg = __fdividef(zv, 1.f + __expf(-zv));
    *yp = f2bf((((y0+y1)+(y2+y3)) + uv*Dd) * sg);
    yp += sst;
    dv = dvn; uv = uvn; zv = zvn;
  }
}

// -------------------------------------------------------------------------------
extern "C" void kernel_launch(void* const* d_in, const int* in_sizes, int n_in,
                              void* d_out, int out_size, void* d_ws, size_t ws_size,
                              hipStream_t stream) {
  const float* x       = (const float*)d_in[0];
  const float* norm_w  = (const float*)d_in[1];
  const float* norm_b  = (const float*)d_in[2];
  const float* fus_w   = (const float*)d_in[3];
  const float* fus_b   = (const float*)d_in[4];
  const float* f_in_w  = (const float*)d_in[5];
  const float* f_conv_w= (const float*)d_in[6];
  const float* f_conv_b= (const float*)d_in[7];
  const float* f_xproj = (const float*)d_in[8];
  const float* f_dt_w  = (const float*)d_in[9];
  const float* f_dt_b  = (const float*)d_in[10];
  const float* f_A_log = (const float*)d_in[11];
  const float* f_D     = (const float*)d_in[12];
  const float* f_out_w = (const float*)d_in[13];
  const float* b_in_w  = (const float*)d_in[14];
  const float* b_conv_w= (const float*)d_in[15];
  const float* b_conv_b= (const float*)d_in[16];
  const float* b_xproj = (const float*)d_in[17];
  const float* b_dt_w  = (const float*)d_in[18];
  const float* b_dt_b  = (const float*)d_in[19];
  const float* b_A_log = (const float*)d_in[20];
  const float* b_D     = (const float*)d_in[21];
  const float* b_out_w = (const float*)d_in[22];

  // ---- workspace carve (fp32 then bf16 regions) ----
  float* xz    = (float*)d_ws;                        // 2*M*1024
  float* u_f   = xz   + (size_t)2*M_*1024;            // 2*M*512
  float* delta = u_f  + (size_t)2*M_*DI;              // 2*M*512
  float* xdbl  = delta+ (size_t)2*M_*DI;              // 2*M*64
  float* Pb    = xdbl + (size_t)2*M_*XDS;             // NCH*65536
  float* qb    = Pb   + (size_t)NCH*65536;
  float* hsb   = qb   + (size_t)NCH*65536;
  unsigned short* xn_bf  = (unsigned short*)(hsb + (size_t)NCH*65536);  // M*256
  unsigned short* u_bf   = xn_bf  + (size_t)M_*DM;    // 2*M*512
  unsigned short* y_bf   = u_bf   + (size_t)2*M_*DI;  // 2*M*512
  unsigned short* xcat_bf= y_bf   + (size_t)2*M_*DI;  // M*512
  unsigned short* w_bf   = xcat_bf+ (size_t)M_*DI;    // 983040
  unsigned short* wf_in  = w_bf;
  unsigned short* wb_in  = w_bf + 262144;
  unsigned short* wf_out = w_bf + 524288;
  unsigned short* wb_out = w_bf + 655360;
  unsigned short* wfus   = w_bf + 786432;
  unsigned short* wf_xp  = w_bf + 917504;
  unsigned short* wb_xp  = w_bf + 950272;

  // 0. weights -> bf16 (incl. zero-padded xproj to 64 rows)
  wconv_kernel<<<3840, 256, 0, stream>>>(f_in_w, b_in_w, f_out_w, b_out_w,
                                         fus_w, f_xproj, b_xproj, w_bf);

  // 1. LayerNorm -> bf16
  ln_kernel<<<M_, 64, 0, stream>>>(x, norm_w, norm_b, xn_bf);

  // 2. in-proj GEMMs: xz_dir = xn @ in_w^T  (M x 1024), fp32 out
  gemm_mfma<float><<<dim3(1024/GBN, M_/GBM), 256, 0, stream>>>(
      xn_bf, DM, wf_in, DM, xz, 1024, DM, nullptr, nullptr, 0);
  gemm_mfma<float><<<dim3(1024/GBN, M_/GBM), 256, 0, stream>>>(
      xn_bf, DM, wb_in, DM, xz + (size_t)M_*1024, 1024, DM, nullptr, nullptr, 0);

  // 3. depthwise conv + SiLU -> fp32 u + bf16 u
  conv_silu_kernel<<<dim3(M_*DI/256, 2), 256, 0, stream>>>(
      xz, f_conv_w, f_conv_b, b_conv_w, b_conv_b, u_f, u_bf);

  // 4. x-proj: xdbl = u @ xproj_pad^T (N=64, stride 64), fp32 out
  gemm_mfma<float><<<dim3(1, M_/GBM), 256, 0, stream>>>(
      u_bf, DI, wf_xp, DI, xdbl, XDS, DI, nullptr, nullptr, 0);
  gemm_mfma<float><<<dim3(1, M_/GBM), 256, 0, stream>>>(
      u_bf + (size_t)M_*DI, DI, wb_xp, DI, xdbl + (size_t)M_*XDS, XDS, DI, nullptr, nullptr, 0);

  // 5. delta = softplus(dt @ dt_w^T + dt_b)
  delta_kernel<<<2*M_*DI/256, 256, 0, stream>>>(xdbl, f_dt_w, f_dt_b, b_dt_w, b_dt_b, delta);

  // 6. chunked scan (states in registers) -> bf16 y
  scanA_kernel<<<dim3(16, NCH), 256, 0, stream>>>(delta, u_f, xdbl, f_A_log, b_A_log, Pb, qb);
  scanB_kernel<<<256, 256, 0, stream>>>(Pb, qb, hsb);
  scanC_kernel<<<dim3(16, NCH), 256, 0, stream>>>(delta, u_f, xdbl, xz, f_A_log, b_A_log,
                                                  f_D, b_D, hsb, y_bf);

  // 7. out-proj GEMMs -> bf16 concat buffer
  gemm_mfma<unsigned short><<<dim3(256/GBN, M_/GBM), 256, 0, stream>>>(
      y_bf, DI, wf_out, DI, xcat_bf, 512, DI, nullptr, nullptr, 0);
  gemm_mfma<unsigned short><<<dim3(256/GBN, M_/GBM), 256, 0, stream>>>(
      y_bf + (size_t)M_*DI, DI, wb_out, DI, xcat_bf + 256, 512, DI, nullptr, nullptr, 0);

  // 8. fusion GEMM + bias + residual -> fp32 out
  gemm_mfma<float><<<dim3(256/GBN, M_/GBM), 256, 0, stream>>>(
      xcat_bf, DI, wfus, DI, (float*)d_out, 256, DI, fus_b, x, DM);
}